// Round 6
// baseline (12924.428 us; speedup 1.0000x reference)
//
#include <hip/hip_runtime.h>
#include <hip/hip_bf16.h>
#include <type_traits>

// Model_50981261804324: PatchTST-style model forward.
// B=16, L=512, d_model=768, d_ff=3072, gate_dff=512, heads=12, dh=64.
// Round 6: OUTPUT IS FLOAT32 (reference returns jnp.float32; stub: "else
// float*"). The "bf16" in the test label is the tolerance policy, not the
// buffer dtype. Rounds 2-5 wrote bf16 into an f32-read buffer -> deterministic
// scramble (read[i] ~= my[2i+1]) exactly matching the observed 1.855469
// invariant absmax. Inputs fp32 dict-order (confirmed r1/r4).

using bf16 = __hip_bfloat16;

#define BB   16
#define LL   512
#define DM   768
#define DFF  3072
#define DLLM 1024
#define GDFF 512
#define NH   12
#define DH   64

__device__ __forceinline__ float b2f(bf16 x) { return __bfloat162float(x); }
__device__ __forceinline__ bf16  f2b(float x) { return __float2bfloat16(x); }
__device__ __forceinline__ float braw2f(unsigned short r) {
  union { unsigned u; float f; } c; c.u = ((unsigned)r) << 16; return c.f;
}
__device__ __forceinline__ float toF(float x) { return x; }
__device__ __forceinline__ float toF(bf16 x) { return b2f(x); }

__device__ __forceinline__ float gelu_tanh(float x) {
  float x3 = x * x * x;
  return 0.5f * x * (1.f + tanhf(0.7978845608028654f * (x + 0.044715f * x3)));
}

// ---------------------------------------------------------------------------
// dkp = DKP_embeddings[16,1024] @ W_gate[1024,512]  (tiny)
__global__ __launch_bounds__(256) void dkp_kernel(const float* __restrict__ E,
                                                  const float* __restrict__ Wg,
                                                  float* __restrict__ dkp) {
  int idx = blockIdx.x * 256 + threadIdx.x;      // 8192
  int b = idx >> 9, n = idx & 511;
  const float* e = E + b * DLLM;
  float acc = 0.f;
  for (int k = 0; k < DLLM; ++k) acc += e[k] * Wg[k * GDFF + n];
  dkp[idx] = acc;
}

// gate[b][n] = sigmoid(dkp[b] . Wg[:,n] + bg[n]) * km(b,n)
__global__ __launch_bounds__(256) void gate_kernel(const float* __restrict__ dkp,
                                                   const float* __restrict__ Wg,
                                                   const float* __restrict__ bg,
                                                   const int* __restrict__ cm,
                                                   float* __restrict__ gout) {
  int idx = blockIdx.x * 256 + threadIdx.x;      // 16*3072
  int b = idx / DFF, n = idx % DFF;
  const float* d = dkp + b * GDFF;
  float acc = 0.f;
  for (int k = 0; k < GDFF; ++k) acc += d[k] * Wg[k * DFF + n];
  acc += bg[n];
  float g = 1.f / (1.f + expf(-acc));
  float km = (n < 1280) ? (float)cm[b * 20 + (n >> 6)] : 1.f;
  gout[idx] = g * km;
}

// ---------------------------------------------------------------------------
// Generic tiled GEMM: C[M,N] = epilogue(A[M,K] @ W[K,N] + bias)
// MODE 0: C = acc + bias
// MODE 1: C = gelu(acc + bias) * gate[batch(row)*DFF + col]   (N must be DFF)
// MODE 2: C = acc + bias + res[row*N + col]
template <typename AT, typename CT, int MODE>
__global__ __launch_bounds__(256) void gemm_kernel(
    const AT* __restrict__ A, const float* __restrict__ W,
    const float* __restrict__ bias, const float* __restrict__ gate,
    const float* res, const float* __restrict__ rowscale,
    CT* C, int M, int N, int K) {
  __shared__ float As[16][68];   // [k][m]
  __shared__ float Ws[16][68];   // [k][n]
  const int t = threadIdx.x;
  const int n0 = blockIdx.x * 64;
  const int m0 = blockIdx.y * 64;
  const int tx = t & 15, ty = t >> 4;
  const int am = t >> 2, ak = (t & 3) * 4;   // A loader: row am, 4 k's
  const int wk = t >> 4, wn = (t & 15) * 4;  // W loader: row wk, 4 n's

  float acc[16];
#pragma unroll
  for (int i = 0; i < 16; ++i) acc[i] = 0.f;

  float ascale = 1.f;
  if (rowscale) ascale = rowscale[m0 + am];
  const AT* Arow = A + (size_t)(m0 + am) * K;

  for (int k0 = 0; k0 < K; k0 += 16) {
    float av[4], wv[4];
    if (k0 + 16 <= K) {
      if constexpr (std::is_same<AT, float>::value) {
        float4 a4 = *reinterpret_cast<const float4*>(Arow + k0 + ak);
        av[0] = a4.x; av[1] = a4.y; av[2] = a4.z; av[3] = a4.w;
      } else {
        ushort4 a4 = *reinterpret_cast<const ushort4*>(
            reinterpret_cast<const unsigned short*>(Arow) + k0 + ak);
        av[0] = braw2f(a4.x); av[1] = braw2f(a4.y);
        av[2] = braw2f(a4.z); av[3] = braw2f(a4.w);
      }
      float4 w4 = *reinterpret_cast<const float4*>(
          W + (size_t)(k0 + wk) * N + n0 + wn);
      wv[0] = w4.x; wv[1] = w4.y; wv[2] = w4.z; wv[3] = w4.w;
    } else {  // K tail (K=900)
#pragma unroll
      for (int i = 0; i < 4; ++i) {
        int kk = k0 + ak + i;
        av[i] = (kk < K) ? toF(Arow[kk]) : 0.f;
      }
      int kw = k0 + wk;
#pragma unroll
      for (int j = 0; j < 4; ++j)
        wv[j] = (kw < K) ? W[(size_t)kw * N + n0 + wn + j] : 0.f;
    }
    __syncthreads();
#pragma unroll
    for (int i = 0; i < 4; ++i) As[ak + i][am] = av[i] * ascale;
#pragma unroll
    for (int j = 0; j < 4; ++j) Ws[wk][wn + j] = wv[j];
    __syncthreads();
#pragma unroll
    for (int kk = 0; kk < 16; ++kk) {
      float a[4], b[4];
#pragma unroll
      for (int i = 0; i < 4; ++i) a[i] = As[kk][ty * 4 + i];
#pragma unroll
      for (int j = 0; j < 4; ++j) b[j] = Ws[kk][tx * 4 + j];
#pragma unroll
      for (int i = 0; i < 4; ++i)
#pragma unroll
        for (int j = 0; j < 4; ++j) acc[i * 4 + j] = fmaf(a[i], b[j], acc[i * 4 + j]);
    }
  }

  const int gb = (m0 >> 9) * DFF;  // 64-row tile lies in a single batch (512 | 64)
#pragma unroll
  for (int i = 0; i < 4; ++i) {
    int r = m0 + ty * 4 + i;
#pragma unroll
    for (int j = 0; j < 4; ++j) {
      int c = n0 + tx * 4 + j;
      float v = acc[i * 4 + j] + bias[c];
      if constexpr (MODE == 1) v = gelu_tanh(v) * gate[gb + c];
      if constexpr (MODE == 2) v += res[(size_t)r * N + c];
      if constexpr (std::is_same<CT, float>::value) C[(size_t)r * N + c] = v;
      else C[(size_t)r * N + c] = f2b(v);
    }
  }
}

// ---------------------------------------------------------------------------
// LayerNorm (no affine): one block per row of 768. In-place safe.
__global__ __launch_bounds__(256) void ln_kernel(const float* src, float* dst) {
  __shared__ float rs[256], rq[256];
  const int row = blockIdx.x, t = threadIdx.x;
  const float* p = src + (size_t)row * DM;
  float x0 = p[t], x1 = p[t + 256], x2 = p[t + 512];
  rs[t] = x0 + x1 + x2;
  rq[t] = x0 * x0 + x1 * x1 + x2 * x2;
  __syncthreads();
  for (int off = 128; off; off >>= 1) {
    if (t < off) { rs[t] += rs[t + off]; rq[t] += rq[t + off]; }
    __syncthreads();
  }
  float mean = rs[0] * (1.f / 768.f);
  float var = rq[0] * (1.f / 768.f) - mean * mean;
  float inv = rsqrtf(var + 1e-5f);
  float* q = dst + (size_t)row * DM;
  q[t] = (x0 - mean) * inv;
  q[t + 256] = (x1 - mean) * inv;
  q[t + 512] = (x2 - mean) * inv;
}

// out += sinusoidal PE (pos = row % 512)
__global__ __launch_bounds__(256) void pe_kernel(float* __restrict__ out) {
  int idx = blockIdx.x * 256 + threadIdx.x;
  int c = idx % DM;
  int l = (idx / DM) & (LL - 1);
  float freq = expf((float)(c & ~1) * (-9.210340371976184f / 768.f));
  float ang = (float)l * freq;
  out[idx] += (c & 1) ? cosf(ang) : sinf(ang);
}

// ---------------------------------------------------------------------------
// Simple attention: one wave per Q row; lane = head dim (0..63).
// grid (L/4, NH, B), block 256 (= 4 waves = 4 Q rows). Online softmax with
// wave-uniform scalars; K/V reads coalesced 128B/wave. No LDS, no barriers.
__global__ __launch_bounds__(256) void attn_kernel(const bf16* __restrict__ q,
                                                   const bf16* __restrict__ k,
                                                   const bf16* __restrict__ v,
                                                   const float* __restrict__ mask,
                                                   float* __restrict__ o) {
  const int w = threadIdx.x >> 6;          // wave id 0..3
  const int lane = threadIdx.x & 63;       // head dim
  const int qrow = blockIdx.x * 4 + w;     // 0..511
  const int hh = blockIdx.y, b = blockIdx.z;
  const unsigned short* qr = reinterpret_cast<const unsigned short*>(q);
  const unsigned short* kr = reinterpret_cast<const unsigned short*>(k);
  const unsigned short* vr = reinterpret_cast<const unsigned short*>(v);
  const size_t base = (size_t)(b * LL) * DM + hh * DH;

  const float qv = braw2f(qr[base + (size_t)qrow * DM + lane]) * 0.125f;
  float m = -1e30f, l = 0.f, acc = 0.f;

  for (int key = 0; key < LL; ++key) {
    const size_t koff = base + (size_t)key * DM + lane;
    float s = qv * braw2f(kr[koff]);
    s += __shfl_xor(s, 1);  s += __shfl_xor(s, 2);  s += __shfl_xor(s, 4);
    s += __shfl_xor(s, 8);  s += __shfl_xor(s, 16); s += __shfl_xor(s, 32);
    if (mask[b * LL + key] == 0.f) s = -1e9f;
    float nm = fmaxf(m, s);
    float alpha = expf(m - nm);
    float p = expf(s - nm);
    acc = acc * alpha + p * braw2f(vr[koff]);
    l = l * alpha + p;
    m = nm;
  }
  o[base + (size_t)qrow * DM + lane] = acc / l;
}

// ---------------------------------------------------------------------------
// Final: per-batch gather last valid row, LN, head matmul. Writes FP32 out.
__global__ __launch_bounds__(256) void final_kernel(const float* __restrict__ out,
                                                    const float* __restrict__ mask,
                                                    const float* __restrict__ Wh,
                                                    const float* __restrict__ bh,
                                                    float* __restrict__ dout) {
  __shared__ float rs[256], rq[256];
  const int b = blockIdx.x, t = threadIdx.x;
  rs[t] = mask[b * LL + t] + mask[b * LL + 256 + t];
  __syncthreads();
  for (int off = 128; off; off >>= 1) {
    if (t < off) rs[t] += rs[t + off];
    __syncthreads();
  }
  int idx = (int)(rs[0] + 0.5f) - 1;
  if (idx < 0) idx = 0;
  __syncthreads();

  const float* row = out + ((size_t)b * LL + idx) * DM;
  float x0 = row[t], x1 = row[t + 256], x2 = row[t + 512];
  rs[t] = x0 + x1 + x2;
  rq[t] = x0 * x0 + x1 * x1 + x2 * x2;
  __syncthreads();
  for (int off = 128; off; off >>= 1) {
    if (t < off) { rs[t] += rs[t + off]; rq[t] += rq[t + off]; }
    __syncthreads();
  }
  float mean = rs[0] * (1.f / 768.f);
  float var = rq[0] * (1.f / 768.f) - mean * mean;
  float inv = rsqrtf(var + 1e-5f);
  float y0 = (x0 - mean) * inv, y1 = (x1 - mean) * inv, y2 = (x2 - mean) * inv;
  dout[16 + b * DM + t] = y0;
  dout[16 + b * DM + 256 + t] = y1;
  dout[16 + b * DM + 512 + t] = y2;
  __syncthreads();
  rs[t] = y0 * Wh[t] + y1 * Wh[t + 256] + y2 * Wh[t + 512];
  __syncthreads();
  for (int off = 128; off; off >>= 1) {
    if (t < off) rs[t] += rs[t + off];
    __syncthreads();
  }
  if (t == 0) dout[b] = rs[0] + bh[0];
}

// ---------------------------------------------------------------------------
extern "C" void kernel_launch(void* const* d_in, const int* in_sizes, int n_in,
                              void* d_out, int out_size, void* d_ws, size_t ws_size,
                              hipStream_t stream) {
  const float* ccd    = (const float*)d_in[0];
  const float* mask   = (const float*)d_in[1];
  const float* dkpE   = (const float*)d_in[2];
  const int*   cmask  = (const int*)d_in[3];
  const float* W_gate = (const float*)d_in[4];
  const float* We1 = (const float*)d_in[5];
  const float* be1 = (const float*)d_in[6];
  const float* Weg = (const float*)d_in[7];
  const float* beg = (const float*)d_in[8];
  const float* We2 = (const float*)d_in[9];
  const float* be2 = (const float*)d_in[10];
  const float* Wm1 = (const float*)d_in[11];
  const float* bm1 = (const float*)d_in[12];
  const float* Wmg = (const float*)d_in[13];
  const float* bmg = (const float*)d_in[14];
  const float* Wm2 = (const float*)d_in[15];
  const float* bm2 = (const float*)d_in[16];
  const float* Wq = (const float*)d_in[17];   // dict order (confirmed r4)
  const float* Wk = (const float*)d_in[18];
  const float* Wv = (const float*)d_in[19];
  const float* Wo = (const float*)d_in[20];
  const float* bq = (const float*)d_in[21];
  const float* bk = (const float*)d_in[22];
  const float* bv = (const float*)d_in[23];
  const float* bo = (const float*)d_in[24];
  const float* Wf1 = (const float*)d_in[25];
  const float* bf1 = (const float*)d_in[26];
  const float* Wfg = (const float*)d_in[27];
  const float* bfg = (const float*)d_in[28];
  const float* Wf2 = (const float*)d_in[29];
  const float* bf2 = (const float*)d_in[30];
  const float* W_head = (const float*)d_in[31];
  const float* b_head = (const float*)d_in[32];

  // workspace layout (~102 MB): q/k/v alias into ubuf (lifetimes disjoint)
  const size_t need = (size_t)8192 * 4 + (size_t)5 * 16 * DFF * 4 +
                      (size_t)8192 * DM * 4 * 2 + (size_t)8192 * DFF * 2;
  if (ws_size < need) return;  // diagnostic: zero output => ws too small

  char* wsb = (char*)d_ws;
  float* dkp   = (float*)wsb; wsb += (size_t)8192 * 4;
  float* gates = (float*)wsb; wsb += (size_t)5 * 16 * DFF * 4;
  float* out   = (float*)wsb; wsb += (size_t)8192 * DM * 4;
  float* hbuf  = (float*)wsb; wsb += (size_t)8192 * DM * 4;
  bf16*  ubuf  = (bf16*)wsb;  wsb += (size_t)8192 * DFF * 2;
  bf16* qb = ubuf;
  bf16* kb = ubuf + (size_t)8192 * DM;
  bf16* vb = ubuf + (size_t)2 * 8192 * DM;

  dim3 blk(256);

  // gates
  dkp_kernel<<<32, blk, 0, stream>>>(dkpE, W_gate, dkp);
  const float* Wgs[5] = {Weg, Wmg, Wmg + (size_t)GDFF * DFF, Wfg, Wfg + (size_t)GDFF * DFF};
  const float* bgs[5] = {beg, bmg, bmg + DFF, bfg, bfg + DFF};
  for (int g = 0; g < 5; ++g)
    gate_kernel<<<192, blk, 0, stream>>>(dkp, Wgs[g], bgs[g], cmask, gates + (size_t)g * 16 * DFF);

  // patch embed gated FFN: u = gelu(x@We1+be1)*g_e ; out = u@We2+be2
  gemm_kernel<float, bf16, 1><<<dim3(48, 128), blk, 0, stream>>>(
      ccd, We1, be1, gates, nullptr, mask, ubuf, 8192, DFF, 900);
  gemm_kernel<bf16, float, 0><<<dim3(12, 128), blk, 0, stream>>>(
      ubuf, We2, be2, nullptr, nullptr, nullptr, out, 8192, DM, DFF);

  // intra MLP blocks: out += gated_ffn(ln(out))
  for (int i = 0; i < 2; ++i) {
    ln_kernel<<<8192, blk, 0, stream>>>(out, hbuf);
    gemm_kernel<float, bf16, 1><<<dim3(48, 128), blk, 0, stream>>>(
        hbuf, Wm1 + (size_t)i * DM * DFF, bm1 + i * DFF, gates + (size_t)(1 + i) * 16 * DFF,
        nullptr, nullptr, ubuf, 8192, DFF, DM);
    gemm_kernel<bf16, float, 2><<<dim3(12, 128), blk, 0, stream>>>(
        ubuf, Wm2 + (size_t)i * DFF * DM, bm2 + i * DM, nullptr, out, nullptr, out, 8192, DM, DFF);
  }

  pe_kernel<<<24576, blk, 0, stream>>>(out);

  // encoder layers
  for (int i = 0; i < 2; ++i) {
    size_t wof = (size_t)i * DM * DM;
    gemm_kernel<float, bf16, 0><<<dim3(12, 128), blk, 0, stream>>>(
        out, Wq + wof, bq + i * DM, nullptr, nullptr, nullptr, qb, 8192, DM, DM);
    gemm_kernel<float, bf16, 0><<<dim3(12, 128), blk, 0, stream>>>(
        out, Wk + wof, bk + i * DM, nullptr, nullptr, nullptr, kb, 8192, DM, DM);
    gemm_kernel<float, bf16, 0><<<dim3(12, 128), blk, 0, stream>>>(
        out, Wv + wof, bv + i * DM, nullptr, nullptr, nullptr, vb, 8192, DM, DM);
    attn_kernel<<<dim3(128, 12, 16), blk, 0, stream>>>(qb, kb, vb, mask, hbuf);
    gemm_kernel<float, float, 2><<<dim3(12, 128), blk, 0, stream>>>(
        hbuf, Wo + wof, bo + i * DM, nullptr, out, nullptr, out, 8192, DM, DM);
    ln_kernel<<<8192, blk, 0, stream>>>(out, out);
    gemm_kernel<float, bf16, 1><<<dim3(48, 128), blk, 0, stream>>>(
        out, Wf1 + (size_t)i * DM * DFF, bf1 + i * DFF, gates + (size_t)(3 + i) * 16 * DFF,
        nullptr, nullptr, ubuf, 8192, DFF, DM);
    gemm_kernel<bf16, float, 2><<<dim3(12, 128), blk, 0, stream>>>(
        ubuf, Wf2 + (size_t)i * DFF * DM, bf2 + i * DM, nullptr, out, nullptr, out, 8192, DM, DFF);
    ln_kernel<<<8192, blk, 0, stream>>>(out, out);
  }

  final_kernel<<<16, blk, 0, stream>>>(out, mask, W_head, b_head, (float*)d_out);
}

// Round 7
// 7543.325 us; speedup vs baseline: 1.7134x; 1.7134x over previous
//
#include <hip/hip_runtime.h>
#include <hip/hip_bf16.h>
#include <type_traits>

// Model_50981261804324: PatchTST-style model forward.
// B=16, L=512, d_model=768, d_ff=3072, gate_dff=512, heads=12, dh=64.
// Round 7: harness contract pinned (fp32 in / fp32 out / dict order).
// Optimization: restore flash-tile attention (r4 structure) replacing the
// shuffle-per-key wave attention (was 2x3610us, 56% of runtime, VALU-bound).

using bf16 = __hip_bfloat16;

#define BB   16
#define LL   512
#define DM   768
#define DFF  3072
#define DLLM 1024
#define GDFF 512
#define NH   12
#define DH   64

__device__ __forceinline__ float b2f(bf16 x) { return __bfloat162float(x); }
__device__ __forceinline__ bf16  f2b(float x) { return __float2bfloat16(x); }
__device__ __forceinline__ float braw2f(unsigned short r) {
  union { unsigned u; float f; } c; c.u = ((unsigned)r) << 16; return c.f;
}
__device__ __forceinline__ float toF(float x) { return x; }
__device__ __forceinline__ float toF(bf16 x) { return b2f(x); }

__device__ __forceinline__ float gelu_tanh(float x) {
  float x3 = x * x * x;
  return 0.5f * x * (1.f + tanhf(0.7978845608028654f * (x + 0.044715f * x3)));
}

// ---------------------------------------------------------------------------
// dkp = DKP_embeddings[16,1024] @ W_gate[1024,512]  (tiny)
__global__ __launch_bounds__(256) void dkp_kernel(const float* __restrict__ E,
                                                  const float* __restrict__ Wg,
                                                  float* __restrict__ dkp) {
  int idx = blockIdx.x * 256 + threadIdx.x;      // 8192
  int b = idx >> 9, n = idx & 511;
  const float* e = E + b * DLLM;
  float acc = 0.f;
  for (int k = 0; k < DLLM; ++k) acc += e[k] * Wg[k * GDFF + n];
  dkp[idx] = acc;
}

// gate[b][n] = sigmoid(dkp[b] . Wg[:,n] + bg[n]) * km(b,n)
__global__ __launch_bounds__(256) void gate_kernel(const float* __restrict__ dkp,
                                                   const float* __restrict__ Wg,
                                                   const float* __restrict__ bg,
                                                   const int* __restrict__ cm,
                                                   float* __restrict__ gout) {
  int idx = blockIdx.x * 256 + threadIdx.x;      // 16*3072
  int b = idx / DFF, n = idx % DFF;
  const float* d = dkp + b * GDFF;
  float acc = 0.f;
  for (int k = 0; k < GDFF; ++k) acc += d[k] * Wg[k * DFF + n];
  acc += bg[n];
  float g = 1.f / (1.f + expf(-acc));
  float km = (n < 1280) ? (float)cm[b * 20 + (n >> 6)] : 1.f;
  gout[idx] = g * km;
}

// ---------------------------------------------------------------------------
// Generic tiled GEMM: C[M,N] = epilogue(A[M,K] @ W[K,N] + bias)
// MODE 0: C = acc + bias
// MODE 1: C = gelu(acc + bias) * gate[batch(row)*DFF + col]   (N must be DFF)
// MODE 2: C = acc + bias + res[row*N + col]
template <typename AT, typename CT, int MODE>
__global__ __launch_bounds__(256) void gemm_kernel(
    const AT* __restrict__ A, const float* __restrict__ W,
    const float* __restrict__ bias, const float* __restrict__ gate,
    const float* res, const float* __restrict__ rowscale,
    CT* C, int M, int N, int K) {
  __shared__ float As[16][68];   // [k][m]
  __shared__ float Ws[16][68];   // [k][n]
  const int t = threadIdx.x;
  const int n0 = blockIdx.x * 64;
  const int m0 = blockIdx.y * 64;
  const int tx = t & 15, ty = t >> 4;
  const int am = t >> 2, ak = (t & 3) * 4;   // A loader: row am, 4 k's
  const int wk = t >> 4, wn = (t & 15) * 4;  // W loader: row wk, 4 n's

  float acc[16];
#pragma unroll
  for (int i = 0; i < 16; ++i) acc[i] = 0.f;

  float ascale = 1.f;
  if (rowscale) ascale = rowscale[m0 + am];
  const AT* Arow = A + (size_t)(m0 + am) * K;

  for (int k0 = 0; k0 < K; k0 += 16) {
    float av[4], wv[4];
    if (k0 + 16 <= K) {
      if constexpr (std::is_same<AT, float>::value) {
        float4 a4 = *reinterpret_cast<const float4*>(Arow + k0 + ak);
        av[0] = a4.x; av[1] = a4.y; av[2] = a4.z; av[3] = a4.w;
      } else {
        ushort4 a4 = *reinterpret_cast<const ushort4*>(
            reinterpret_cast<const unsigned short*>(Arow) + k0 + ak);
        av[0] = braw2f(a4.x); av[1] = braw2f(a4.y);
        av[2] = braw2f(a4.z); av[3] = braw2f(a4.w);
      }
      float4 w4 = *reinterpret_cast<const float4*>(
          W + (size_t)(k0 + wk) * N + n0 + wn);
      wv[0] = w4.x; wv[1] = w4.y; wv[2] = w4.z; wv[3] = w4.w;
    } else {  // K tail (K=900)
#pragma unroll
      for (int i = 0; i < 4; ++i) {
        int kk = k0 + ak + i;
        av[i] = (kk < K) ? toF(Arow[kk]) : 0.f;
      }
      int kw = k0 + wk;
#pragma unroll
      for (int j = 0; j < 4; ++j)
        wv[j] = (kw < K) ? W[(size_t)kw * N + n0 + wn + j] : 0.f;
    }
    __syncthreads();
#pragma unroll
    for (int i = 0; i < 4; ++i) As[ak + i][am] = av[i] * ascale;
#pragma unroll
    for (int j = 0; j < 4; ++j) Ws[wk][wn + j] = wv[j];
    __syncthreads();
#pragma unroll
    for (int kk = 0; kk < 16; ++kk) {
      float a[4], b[4];
#pragma unroll
      for (int i = 0; i < 4; ++i) a[i] = As[kk][ty * 4 + i];
#pragma unroll
      for (int j = 0; j < 4; ++j) b[j] = Ws[kk][tx * 4 + j];
#pragma unroll
      for (int i = 0; i < 4; ++i)
#pragma unroll
        for (int j = 0; j < 4; ++j) acc[i * 4 + j] = fmaf(a[i], b[j], acc[i * 4 + j]);
    }
  }

  const int gb = (m0 >> 9) * DFF;  // 64-row tile lies in a single batch (512 | 64)
#pragma unroll
  for (int i = 0; i < 4; ++i) {
    int r = m0 + ty * 4 + i;
#pragma unroll
    for (int j = 0; j < 4; ++j) {
      int c = n0 + tx * 4 + j;
      float v = acc[i * 4 + j] + bias[c];
      if constexpr (MODE == 1) v = gelu_tanh(v) * gate[gb + c];
      if constexpr (MODE == 2) v += res[(size_t)r * N + c];
      if constexpr (std::is_same<CT, float>::value) C[(size_t)r * N + c] = v;
      else C[(size_t)r * N + c] = f2b(v);
    }
  }
}

// ---------------------------------------------------------------------------
// LayerNorm (no affine): one block per row of 768. In-place safe.
__global__ __launch_bounds__(256) void ln_kernel(const float* src, float* dst) {
  __shared__ float rs[256], rq[256];
  const int row = blockIdx.x, t = threadIdx.x;
  const float* p = src + (size_t)row * DM;
  float x0 = p[t], x1 = p[t + 256], x2 = p[t + 512];
  rs[t] = x0 + x1 + x2;
  rq[t] = x0 * x0 + x1 * x1 + x2 * x2;
  __syncthreads();
  for (int off = 128; off; off >>= 1) {
    if (t < off) { rs[t] += rs[t + off]; rq[t] += rq[t + off]; }
    __syncthreads();
  }
  float mean = rs[0] * (1.f / 768.f);
  float var = rq[0] * (1.f / 768.f) - mean * mean;
  float inv = rsqrtf(var + 1e-5f);
  float* q = dst + (size_t)row * DM;
  q[t] = (x0 - mean) * inv;
  q[t + 256] = (x1 - mean) * inv;
  q[t + 512] = (x2 - mean) * inv;
}

// out += sinusoidal PE (pos = row % 512)
__global__ __launch_bounds__(256) void pe_kernel(float* __restrict__ out) {
  int idx = blockIdx.x * 256 + threadIdx.x;
  int c = idx % DM;
  int l = (idx / DM) & (LL - 1);
  float freq = expf((float)(c & ~1) * (-9.210340371976184f / 768.f));
  float ang = (float)l * freq;
  out[idx] += (c & 1) ? cosf(ang) : sinf(ang);
}

// ---------------------------------------------------------------------------
// Flash attention: grid (qt=8, h=12, b=16), 256 threads.
// Q tile 64 rows; thread (ty=row, tx=16-col group). Online softmax.
__global__ __launch_bounds__(256) void flash_kernel(const bf16* __restrict__ q,
                                                    const bf16* __restrict__ k,
                                                    const bf16* __restrict__ v,
                                                    const float* __restrict__ mask,
                                                    float* __restrict__ o) {
  __shared__ float Qs[64][65];
  __shared__ unsigned short Ks[64][66], Vs[64][66];
  __shared__ float Ps[64][65];
  __shared__ float msk[64];
  const int qt = blockIdx.x, hh = blockIdx.y, b = blockIdx.z;
  const int t = threadIdx.x;
  const int ty = t >> 2, tx = t & 3;
  const int c0 = tx * 16;
  const size_t qoff = ((size_t)(b * LL + qt * 64 + ty)) * DM + hh * DH + c0;
  const unsigned short* qr = reinterpret_cast<const unsigned short*>(q);
  const unsigned short* kr = reinterpret_cast<const unsigned short*>(k);
  const unsigned short* vr = reinterpret_cast<const unsigned short*>(v);
#pragma unroll
  for (int i = 0; i < 16; ++i) Qs[ty][c0 + i] = braw2f(qr[qoff + i]) * 0.125f;

  float m = -1e30f, l = 0.f;
  float O[16];
#pragma unroll
  for (int i = 0; i < 16; ++i) O[i] = 0.f;

  for (int kt = 0; kt < 8; ++kt) {
    __syncthreads();  // previous iteration's reads done before overwrite
    const size_t koff = ((size_t)(b * LL + kt * 64 + ty)) * DM + hh * DH + c0;
#pragma unroll
    for (int i = 0; i < 16; ++i) {
      Ks[ty][c0 + i] = kr[koff + i];
      Vs[ty][c0 + i] = vr[koff + i];
    }
    if (t < 64) msk[t] = mask[b * LL + kt * 64 + t];
    __syncthreads();

    float s[16];
#pragma unroll
    for (int j = 0; j < 16; ++j) {
      int kc = c0 + j;
      float a = 0.f;
#pragma unroll 8
      for (int d = 0; d < 64; ++d) a = fmaf(Qs[ty][d], braw2f(Ks[kc][d]), a);
      s[j] = (msk[kc] == 0.f) ? -1e9f : a;
    }
    float rmax = s[0];
#pragma unroll
    for (int j = 1; j < 16; ++j) rmax = fmaxf(rmax, s[j]);
    rmax = fmaxf(rmax, __shfl_xor(rmax, 1));
    rmax = fmaxf(rmax, __shfl_xor(rmax, 2));
    float nm = fmaxf(m, rmax);
    float alpha = expf(m - nm);
    float ps = 0.f;
#pragma unroll
    for (int j = 0; j < 16; ++j) {
      float pv = expf(s[j] - nm);
      Ps[ty][c0 + j] = pv;
      ps += pv;
    }
    ps += __shfl_xor(ps, 1);
    ps += __shfl_xor(ps, 2);
    l = l * alpha + ps;
    m = nm;
#pragma unroll
    for (int i = 0; i < 16; ++i) O[i] *= alpha;
    __syncthreads();  // Ps visible across the row quad
#pragma unroll 4
    for (int kk = 0; kk < 64; ++kk) {
      float pv = Ps[ty][kk];
#pragma unroll
      for (int i = 0; i < 16; ++i) O[i] = fmaf(pv, braw2f(Vs[kk][c0 + i]), O[i]);
    }
  }
  float inv = 1.f / l;
  float* op = o + qoff;
#pragma unroll
  for (int i = 0; i < 16; ++i) op[i] = O[i] * inv;
}

// ---------------------------------------------------------------------------
// Final: per-batch gather last valid row, LN, head matmul. Writes FP32 out.
__global__ __launch_bounds__(256) void final_kernel(const float* __restrict__ out,
                                                    const float* __restrict__ mask,
                                                    const float* __restrict__ Wh,
                                                    const float* __restrict__ bh,
                                                    float* __restrict__ dout) {
  __shared__ float rs[256], rq[256];
  const int b = blockIdx.x, t = threadIdx.x;
  rs[t] = mask[b * LL + t] + mask[b * LL + 256 + t];
  __syncthreads();
  for (int off = 128; off; off >>= 1) {
    if (t < off) rs[t] += rs[t + off];
    __syncthreads();
  }
  int idx = (int)(rs[0] + 0.5f) - 1;
  if (idx < 0) idx = 0;
  __syncthreads();

  const float* row = out + ((size_t)b * LL + idx) * DM;
  float x0 = row[t], x1 = row[t + 256], x2 = row[t + 512];
  rs[t] = x0 + x1 + x2;
  rq[t] = x0 * x0 + x1 * x1 + x2 * x2;
  __syncthreads();
  for (int off = 128; off; off >>= 1) {
    if (t < off) { rs[t] += rs[t + off]; rq[t] += rq[t + off]; }
    __syncthreads();
  }
  float mean = rs[0] * (1.f / 768.f);
  float var = rq[0] * (1.f / 768.f) - mean * mean;
  float inv = rsqrtf(var + 1e-5f);
  float y0 = (x0 - mean) * inv, y1 = (x1 - mean) * inv, y2 = (x2 - mean) * inv;
  dout[16 + b * DM + t] = y0;
  dout[16 + b * DM + 256 + t] = y1;
  dout[16 + b * DM + 512 + t] = y2;
  __syncthreads();
  rs[t] = y0 * Wh[t] + y1 * Wh[t + 256] + y2 * Wh[t + 512];
  __syncthreads();
  for (int off = 128; off; off >>= 1) {
    if (t < off) rs[t] += rs[t + off];
    __syncthreads();
  }
  if (t == 0) dout[b] = rs[0] + bh[0];
}

// ---------------------------------------------------------------------------
extern "C" void kernel_launch(void* const* d_in, const int* in_sizes, int n_in,
                              void* d_out, int out_size, void* d_ws, size_t ws_size,
                              hipStream_t stream) {
  const float* ccd    = (const float*)d_in[0];
  const float* mask   = (const float*)d_in[1];
  const float* dkpE   = (const float*)d_in[2];
  const int*   cmask  = (const int*)d_in[3];
  const float* W_gate = (const float*)d_in[4];
  const float* We1 = (const float*)d_in[5];
  const float* be1 = (const float*)d_in[6];
  const float* Weg = (const float*)d_in[7];
  const float* beg = (const float*)d_in[8];
  const float* We2 = (const float*)d_in[9];
  const float* be2 = (const float*)d_in[10];
  const float* Wm1 = (const float*)d_in[11];
  const float* bm1 = (const float*)d_in[12];
  const float* Wmg = (const float*)d_in[13];
  const float* bmg = (const float*)d_in[14];
  const float* Wm2 = (const float*)d_in[15];
  const float* bm2 = (const float*)d_in[16];
  const float* Wq = (const float*)d_in[17];   // dict order (confirmed r4)
  const float* Wk = (const float*)d_in[18];
  const float* Wv = (const float*)d_in[19];
  const float* Wo = (const float*)d_in[20];
  const float* bq = (const float*)d_in[21];
  const float* bk = (const float*)d_in[22];
  const float* bv = (const float*)d_in[23];
  const float* bo = (const float*)d_in[24];
  const float* Wf1 = (const float*)d_in[25];
  const float* bf1 = (const float*)d_in[26];
  const float* Wfg = (const float*)d_in[27];
  const float* bfg = (const float*)d_in[28];
  const float* Wf2 = (const float*)d_in[29];
  const float* bf2 = (const float*)d_in[30];
  const float* W_head = (const float*)d_in[31];
  const float* b_head = (const float*)d_in[32];

  // workspace layout (~102 MB): q/k/v alias into ubuf (lifetimes disjoint)
  const size_t need = (size_t)8192 * 4 + (size_t)5 * 16 * DFF * 4 +
                      (size_t)8192 * DM * 4 * 2 + (size_t)8192 * DFF * 2;
  if (ws_size < need) return;  // diagnostic: zero output => ws too small

  char* wsb = (char*)d_ws;
  float* dkp   = (float*)wsb; wsb += (size_t)8192 * 4;
  float* gates = (float*)wsb; wsb += (size_t)5 * 16 * DFF * 4;
  float* out   = (float*)wsb; wsb += (size_t)8192 * DM * 4;
  float* hbuf  = (float*)wsb; wsb += (size_t)8192 * DM * 4;
  bf16*  ubuf  = (bf16*)wsb;  wsb += (size_t)8192 * DFF * 2;
  bf16* qb = ubuf;
  bf16* kb = ubuf + (size_t)8192 * DM;
  bf16* vb = ubuf + (size_t)2 * 8192 * DM;

  dim3 blk(256);

  // gates
  dkp_kernel<<<32, blk, 0, stream>>>(dkpE, W_gate, dkp);
  const float* Wgs[5] = {Weg, Wmg, Wmg + (size_t)GDFF * DFF, Wfg, Wfg + (size_t)GDFF * DFF};
  const float* bgs[5] = {beg, bmg, bmg + DFF, bfg, bfg + DFF};
  for (int g = 0; g < 5; ++g)
    gate_kernel<<<192, blk, 0, stream>>>(dkp, Wgs[g], bgs[g], cmask, gates + (size_t)g * 16 * DFF);

  // patch embed gated FFN: u = gelu(x@We1+be1)*g_e ; out = u@We2+be2
  gemm_kernel<float, bf16, 1><<<dim3(48, 128), blk, 0, stream>>>(
      ccd, We1, be1, gates, nullptr, mask, ubuf, 8192, DFF, 900);
  gemm_kernel<bf16, float, 0><<<dim3(12, 128), blk, 0, stream>>>(
      ubuf, We2, be2, nullptr, nullptr, nullptr, out, 8192, DM, DFF);

  // intra MLP blocks: out += gated_ffn(ln(out))
  for (int i = 0; i < 2; ++i) {
    ln_kernel<<<8192, blk, 0, stream>>>(out, hbuf);
    gemm_kernel<float, bf16, 1><<<dim3(48, 128), blk, 0, stream>>>(
        hbuf, Wm1 + (size_t)i * DM * DFF, bm1 + i * DFF, gates + (size_t)(1 + i) * 16 * DFF,
        nullptr, nullptr, ubuf, 8192, DFF, DM);
    gemm_kernel<bf16, float, 2><<<dim3(12, 128), blk, 0, stream>>>(
        ubuf, Wm2 + (size_t)i * DFF * DM, bm2 + i * DM, nullptr, out, nullptr, out, 8192, DM, DFF);
  }

  pe_kernel<<<24576, blk, 0, stream>>>(out);

  // encoder layers
  for (int i = 0; i < 2; ++i) {
    size_t wof = (size_t)i * DM * DM;
    gemm_kernel<float, bf16, 0><<<dim3(12, 128), blk, 0, stream>>>(
        out, Wq + wof, bq + i * DM, nullptr, nullptr, nullptr, qb, 8192, DM, DM);
    gemm_kernel<float, bf16, 0><<<dim3(12, 128), blk, 0, stream>>>(
        out, Wk + wof, bk + i * DM, nullptr, nullptr, nullptr, kb, 8192, DM, DM);
    gemm_kernel<float, bf16, 0><<<dim3(12, 128), blk, 0, stream>>>(
        out, Wv + wof, bv + i * DM, nullptr, nullptr, nullptr, vb, 8192, DM, DM);
    flash_kernel<<<dim3(8, 12, 16), blk, 0, stream>>>(qb, kb, vb, mask, hbuf);
    gemm_kernel<float, float, 2><<<dim3(12, 128), blk, 0, stream>>>(
        hbuf, Wo + wof, bo + i * DM, nullptr, out, nullptr, out, 8192, DM, DM);
    ln_kernel<<<8192, blk, 0, stream>>>(out, out);
    gemm_kernel<float, bf16, 1><<<dim3(48, 128), blk, 0, stream>>>(
        out, Wf1 + (size_t)i * DM * DFF, bf1 + i * DFF, gates + (size_t)(3 + i) * 16 * DFF,
        nullptr, nullptr, ubuf, 8192, DFF, DM);
    gemm_kernel<bf16, float, 2><<<dim3(12, 128), blk, 0, stream>>>(
        ubuf, Wf2 + (size_t)i * DFF * DM, bf2 + i * DM, nullptr, out, nullptr, out, 8192, DM, DFF);
    ln_kernel<<<8192, blk, 0, stream>>>(out, out);
  }

  final_kernel<<<16, blk, 0, stream>>>(out, mask, W_head, b_head, (float*)d_out);
}